// Round 14
// baseline (481.009 us; speedup 1.0000x reference)
//
#include <hip/hip_runtime.h>
#include <math.h>

#define BSZ 4
#define DM 256
#define LL 256
#define DI 512
#define NBL (BSZ * LL)  // 1024

__device__ __forceinline__ float fast_rcp(float x) { return __builtin_amdgcn_rcpf(x); }
__device__ __forceinline__ float fast_sig(float x) { return fast_rcp(1.0f + __expf(-x)); }

// XCD batch-locality swizzle: launch index j -> (batch b, intra-batch i)
__device__ __forceinline__ void unswz(int j, int& b, int& i) {
    b = (j & 7) >> 1;
    i = ((j >> 3) << 1) | (j & 1);
}

// ---------------- dispatch 1: mean over W -> S0T[b][d][h] (blocks 0..1023) + Wf prep ----------------
__global__ __launch_bounds__(256) void k_meanw_prep(const float* __restrict__ x0,
                                                    const float* __restrict__ in_w1,
                                                    const float* __restrict__ out_w0,
                                                    float* __restrict__ S0T,
                                                    float* __restrict__ Wf) {
    __shared__ float smem[1664];
    int bl = blockIdx.x;
    int tid = threadIdx.x;
    if (bl < 1024) {
        int b, dch; unswz(bl, b, dch);
        int rowblk = (b << 8) | dch;          // x0 row-block (b,d); S0T shares this flat layout
        int wv = tid >> 6, lane = tid & 63;
        const float4* x4 = (const float4*)x0;
        int rbase = rowblk * 256 + wv * 64;
        for (int i0 = 0; i0 < 64; i0 += 8) {
            float s[8];
#pragma unroll
            for (int j = 0; j < 8; ++j) {
                float4 v = x4[(size_t)(rbase + i0 + j) * 64 + lane];
                s[j] = (v.x + v.y) + (v.z + v.w);
            }
#pragma unroll
            for (int j = 0; j < 8; ++j) {
#pragma unroll
                for (int m = 32; m >= 1; m >>= 1) s[j] += __shfl_xor(s[j], m);
            }
            if (lane == 0) {
                float4 o1, o2;
                o1.x = s[0] * (1.0f / 256.0f); o1.y = s[1] * (1.0f / 256.0f);
                o1.z = s[2] * (1.0f / 256.0f); o1.w = s[3] * (1.0f / 256.0f);
                o2.x = s[4] * (1.0f / 256.0f); o2.y = s[5] * (1.0f / 256.0f);
                o2.z = s[6] * (1.0f / 256.0f); o2.w = s[7] * (1.0f / 256.0f);
                *(float4*)(S0T + (size_t)rbase + i0) = o1;
                *(float4*)(S0T + (size_t)rbase + i0 + 4) = o2;
            }
        }
    } else {
        float* As = smem;
        float* Bs = smem + 576;
        int t = bl - 1024;
        int e0 = (t >> 4) * 32, k0c = (t & 15) * 32;
        int tx = tid & 15, ty = tid >> 4;
        float acc00 = 0.f, acc01 = 0.f, acc10 = 0.f, acc11 = 0.f;
        for (int dm0 = 0; dm0 < 256; dm0 += 16) {
            float4 v;
            if (tid < 128) {
                int r = tid >> 2, q = tid & 3;
                v = *(const float4*)(in_w1 + (size_t)(e0 + r) * 256 + dm0 + 4 * q);
            } else {
                int idx = tid - 128;
                int r = idx >> 3, q = idx & 7;
                v = *(const float4*)(out_w0 + (size_t)(dm0 + r) * 512 + k0c + 4 * q);
            }
            __syncthreads();
            if (tid < 128) {
                int r = tid >> 2, q = tid & 3;
                As[(4 * q + 0) * 36 + r] = v.x;
                As[(4 * q + 1) * 36 + r] = v.y;
                As[(4 * q + 2) * 36 + r] = v.z;
                As[(4 * q + 3) * 36 + r] = v.w;
            } else {
                int idx = tid - 128;
                int r = idx >> 3, q = idx & 7;
                Bs[r * 36 + 4 * q + 0] = v.x;
                Bs[r * 36 + 4 * q + 1] = v.y;
                Bs[r * 36 + 4 * q + 2] = v.z;
                Bs[r * 36 + 4 * q + 3] = v.w;
            }
            __syncthreads();
#pragma unroll
            for (int kk = 0; kk < 16; ++kk) {
                float2 a = *(const float2*)(As + kk * 36 + 2 * ty);
                float2 b2 = *(const float2*)(Bs + kk * 36 + 2 * tx);
                acc00 = fmaf(a.x, b2.x, acc00);
                acc01 = fmaf(a.x, b2.y, acc01);
                acc10 = fmaf(a.y, b2.x, acc10);
                acc11 = fmaf(a.y, b2.y, acc11);
            }
        }
        float* c0 = Wf + (size_t)(e0 + 2 * ty) * 512 + k0c + 2 * tx;
        c0[0] = acc00; c0[1] = acc01;
        c0[512] = acc10; c0[513] = acc11;
    }
}

// ---------------- in-proj TN GEMM: xz[(b,l)][e] = sum_d S0T[b][d][l] * in_w[e][d], K=256 ----------------
__global__ __launch_bounds__(256) void k_gemm_tn_inproj(const float* __restrict__ S0T,
                                                        const float* __restrict__ Bw,
                                                        float* __restrict__ C) {
    __shared__ float As[16][68];
    __shared__ float Bs[16][68];
    int tid = threadIdx.x;
    int b, i; unswz(blockIdx.x, b, i);
    int l0 = (i >> 4) * 64;
    int n0 = (i & 15) * 64;
    int m0 = b * 256 + l0;
    int tx = tid & 15, ty = tid >> 4;
    int rkk = tid >> 4, mq = (tid & 15) * 4;
    int rn = tid >> 2, dq = (tid & 3) * 4;

    const float* pa = S0T + ((size_t)(b * 256) + rkk) * 256 + l0 + mq;
    const float* pb = Bw + (size_t)(n0 + rn) * 256 + dq;
    float4 ra = *(const float4*)pa;
    float4 rb = *(const float4*)pb;

    float acc[4][4];
#pragma unroll
    for (int ii = 0; ii < 4; ++ii)
#pragma unroll
        for (int jj = 0; jj < 4; ++jj) acc[ii][jj] = 0.0f;

    for (int d0 = 0; d0 < 256; d0 += 16) {
        __syncthreads();
        *(float4*)(&As[rkk][mq]) = ra;
        Bs[dq + 0][rn] = rb.x; Bs[dq + 1][rn] = rb.y; Bs[dq + 2][rn] = rb.z; Bs[dq + 3][rn] = rb.w;
        __syncthreads();
        if (d0 + 16 < 256) {
            ra = *(const float4*)(pa + (size_t)(d0 + 16) * 256);
            rb = *(const float4*)(pb + d0 + 16);
        }
#pragma unroll
        for (int kk = 0; kk < 16; ++kk) {
            float4 a4 = *(const float4*)(&As[kk][ty * 4]);
            float4 b4 = *(const float4*)(&Bs[kk][tx * 4]);
            float aa[4] = {a4.x, a4.y, a4.z, a4.w};
            float bb[4] = {b4.x, b4.y, b4.z, b4.w};
#pragma unroll
            for (int ii = 0; ii < 4; ++ii)
#pragma unroll
                for (int jj = 0; jj < 4; ++jj)
                    acc[ii][jj] = fmaf(aa[ii], bb[jj], acc[ii][jj]);
        }
    }
#pragma unroll
    for (int ii = 0; ii < 4; ++ii) {
        float4 o;
        o.x = acc[ii][0]; o.y = acc[ii][1]; o.z = acc[ii][2]; o.w = acc[ii][3];
        *(float4*)(C + (size_t)(m0 + ty * 4 + ii) * 1024 + n0 + tx * 4) = o;
    }
}

// ---------------- transition GEMM: 64x64 tile, K=512, grid 256 ----------------
__global__ __launch_bounds__(256) void k_gemm_tn64(const float* __restrict__ At,
                                                   const float* __restrict__ Bw,
                                                   float* __restrict__ C) {
    __shared__ float As[16][68];
    __shared__ float Bs[16][68];
    int tid = threadIdx.x;
    int b, i; unswz(blockIdx.x, b, i);
    int l0 = (i >> 4) * 64;
    int n0 = (i & 15) * 64;
    int m0 = b * 256 + l0;
    int tx = tid & 15, ty = tid >> 4;
    int rkk = tid >> 4, mq = (tid & 15) * 4;
    int rn = tid >> 2, dq = (tid & 3) * 4;

    const float* pa = At + ((size_t)(b * 512) + rkk) * 256 + l0 + mq;
    const float* pb = Bw + (size_t)(n0 + rn) * 512 + dq;
    float4 ra = *(const float4*)pa;
    float4 rb = *(const float4*)pb;

    float acc[4][4];
#pragma unroll
    for (int ii = 0; ii < 4; ++ii)
#pragma unroll
        for (int jj = 0; jj < 4; ++jj) acc[ii][jj] = 0.0f;

    for (int d0 = 0; d0 < 512; d0 += 16) {
        __syncthreads();
        *(float4*)(&As[rkk][mq]) = ra;
        Bs[dq + 0][rn] = rb.x; Bs[dq + 1][rn] = rb.y; Bs[dq + 2][rn] = rb.z; Bs[dq + 3][rn] = rb.w;
        __syncthreads();
        if (d0 + 16 < 512) {
            ra = *(const float4*)(pa + (size_t)(d0 + 16) * 256);
            rb = *(const float4*)(pb + d0 + 16);
        }
#pragma unroll
        for (int kk = 0; kk < 16; ++kk) {
            float4 a4 = *(const float4*)(&As[kk][ty * 4]);
            float4 b4 = *(const float4*)(&Bs[kk][tx * 4]);
            float aa[4] = {a4.x, a4.y, a4.z, a4.w};
            float bb[4] = {b4.x, b4.y, b4.z, b4.w};
#pragma unroll
            for (int ii = 0; ii < 4; ++ii)
#pragma unroll
                for (int jj = 0; jj < 4; ++jj)
                    acc[ii][jj] = fmaf(aa[ii], bb[jj], acc[ii][jj]);
        }
    }
#pragma unroll
    for (int ii = 0; ii < 4; ++ii) {
        float4 o;
        o.x = acc[ii][0]; o.y = acc[ii][1]; o.z = acc[ii][2]; o.w = acc[ii][3];
        *(float4*)(C + (size_t)(m0 + ty * 4 + ii) * 1024 + n0 + tx * 4) = o;
    }
}

// ---------------- mid: conv+silu+xproj -> xdbl only; 256 blocks x 4 (b,l) ----------------
__global__ __launch_bounds__(256) void k_mid(const float* __restrict__ xz,
                                             const float* __restrict__ cw,
                                             const float* __restrict__ cb,
                                             const float* __restrict__ xpw,
                                             float* __restrict__ xdbl) {
    __shared__ float xs[DI];
    __shared__ float pr[256];
    int tid = threadIdx.x;
    int b = (blockIdx.x & 7) >> 1;
    int ib = ((blockIdx.x >> 3) << 1) | (blockIdx.x & 1);   // 0..63

    for (int k = 0; k < 4; ++k) {
        int l = ib + 64 * k;
        int bl = (b << 8) | l;
        __syncthreads();
#pragma unroll
        for (int c = 0; c < 2; ++c) {
            int d = tid + 256 * c;
            float4 w4 = *(const float4*)(cw + d * 4);
            float acc = cb[d];
#pragma unroll
            for (int kk = 0; kk < 4; ++kk) {
                int ls = l + kk - 3;
                float v = (ls >= 0) ? xz[((size_t)(b * LL + ls)) * 1024 + d] : 0.0f;
                acc = fmaf(((const float*)&w4)[kk], v, acc);
            }
            xs[d] = acc * fast_sig(acc);
        }
        __syncthreads();

        int e = tid >> 2, c2 = tid & 3;
        float a = 0.0f;
        if (e < 48) {
            const float4* xv4 = (const float4*)(xs + c2 * 128);
            const float4* wv4 = (const float4*)(xpw + (size_t)e * DI + c2 * 128);
#pragma unroll 8
            for (int q = 0; q < 32; ++q) {
                float4 x4 = xv4[q], p4 = wv4[q];
                a = fmaf(x4.x, p4.x, a);
                a = fmaf(x4.y, p4.y, a);
                a = fmaf(x4.z, p4.z, a);
                a = fmaf(x4.w, p4.w, a);
            }
        }
        pr[tid] = a;
        __syncthreads();
        if (tid < 48)
            xdbl[(size_t)bl * 48 + tid] = pr[4 * tid] + pr[4 * tid + 1] + pr[4 * tid + 2] + pr[4 * tid + 3];
    }
}

// ---------------- scan: 512 blocks x 4 sequences; conv+silu recomputed inline ----------------
__global__ __launch_bounds__(256) void k_scan(const float* __restrict__ xdbl,
                                              const float* __restrict__ xz,
                                              const float* __restrict__ cw,
                                              const float* __restrict__ cb,
                                              const float* __restrict__ Alog,
                                              const float* __restrict__ Dp,
                                              const float* __restrict__ dtw,
                                              const float* __restrict__ dtb,
                                              float* __restrict__ ygT) {
    __shared__ float yred[4][LL];
    __shared__ float us[LL];
    int tid = threadIdx.x;
    int lane = tid & 63, w = tid >> 6;
    int b = (blockIdx.x & 7) >> 1;
    int ib = ((blockIdx.x >> 3) << 1) | (blockIdx.x & 1);   // 0..127
    int l0 = lane * 4;

    for (int kq = 0; kq < 4; ++kq) {
        int d = ib + 128 * kq;
        int seq = b * DI + d;
        __syncthreads();

        const float* xd0 = xdbl + ((size_t)(b * LL) + l0) * 48;
        const float* wr = dtw + d * 16;
        float4 w0 = *(const float4*)(wr + 0);
        float4 w1 = *(const float4*)(wr + 4);
        float4 w2 = *(const float4*)(wr + 8);
        float4 w3 = *(const float4*)(wr + 12);
        float bias = dtb[d];
        float4 w4c = *(const float4*)(cw + d * 4);
        float cbias = cb[d];

        float dt[4], u[4], dtu[4], P[4];
#pragma unroll
        for (int i = 0; i < 4; ++i) {
            const float* xr = xd0 + i * 48;
            float4 a0 = *(const float4*)(xr + 0);
            float4 a1 = *(const float4*)(xr + 4);
            float4 a2 = *(const float4*)(xr + 8);
            float4 a3 = *(const float4*)(xr + 12);
            float acc = bias;
            acc = fmaf(a0.x, w0.x, acc); acc = fmaf(a0.y, w0.y, acc);
            acc = fmaf(a0.z, w0.z, acc); acc = fmaf(a0.w, w0.w, acc);
            acc = fmaf(a1.x, w1.x, acc); acc = fmaf(a1.y, w1.y, acc);
            acc = fmaf(a1.z, w1.z, acc); acc = fmaf(a1.w, w1.w, acc);
            acc = fmaf(a2.x, w2.x, acc); acc = fmaf(a2.y, w2.y, acc);
            acc = fmaf(a2.z, w2.z, acc); acc = fmaf(a2.w, w2.w, acc);
            acc = fmaf(a3.x, w3.x, acc); acc = fmaf(a3.y, w3.y, acc);
            acc = fmaf(a3.z, w3.z, acc); acc = fmaf(a3.w, w3.w, acc);
            dt[i] = (acc > 20.0f) ? acc : __logf(1.0f + __expf(acc));
            // recompute u = silu(conv(xz)) for this channel (bitwise same as k_mid's xs)
            float ua = cbias;
#pragma unroll
            for (int kk = 0; kk < 4; ++kk) {
                int ls = l0 + i + kk - 3;
                float v = (ls >= 0) ? xz[((size_t)(b * LL + ls)) * 1024 + d] : 0.0f;
                ua = fmaf(((const float*)&w4c)[kk], v, ua);
            }
            u[i] = ua * fast_sig(ua);
            dtu[i] = dt[i] * u[i];
        }

        P[0] = dt[0]; P[1] = P[0] + dt[1]; P[2] = P[1] + dt[2]; P[3] = P[2] + dt[3];
        float s = P[3];
#pragma unroll
        for (int off = 1; off < 64; off <<= 1) {
            float t = __shfl_up(s, off);
            if (lane >= off) s += t;
        }
        float base = s - P[3];
        float dt_end = __shfl(s, 63);
        float Dtc[4];
#pragma unroll
        for (int i = 0; i < 4; ++i) Dtc[i] = P[i] + base;

        if (w == 0) {
#pragma unroll
            for (int i = 0; i < 4; ++i) us[l0 + i] = u[i];
        }

        float4 Al = *(const float4*)(Alog + d * 16 + 4 * w);
        float A[4] = {-__expf(Al.x), -__expf(Al.y), -__expf(Al.z), -__expf(Al.w)};
        float Bv[4][4], Cv[4][4];
#pragma unroll
        for (int i = 0; i < 4; ++i) {
            float4 bq = *(const float4*)(xd0 + i * 48 + 16 + 4 * w);
            float4 cq = *(const float4*)(xd0 + i * 48 + 32 + 4 * w);
            Bv[i][0] = bq.x; Bv[i][1] = bq.y; Bv[i][2] = bq.z; Bv[i][3] = bq.w;
            Cv[i][0] = cq.x; Cv[i][1] = cq.y; Cv[i][2] = cq.z; Cv[i][3] = cq.w;
        }

        float y[4] = {0.f, 0.f, 0.f, 0.f};
#pragma unroll
        for (int c = 0; c < 4; ++c) {
            float Ac = A[c];
            float dAc[4], t[4];
#pragma unroll
            for (int i = 0; i < 4; ++i) {
                dAc[i] = __expf(Ac * (dt_end - Dtc[i]));
                t[i] = dtu[i] * Bv[i][c] * dAc[i];
            }
            float p0 = t[0], p1 = p0 + t[1], p2 = p1 + t[2], p3 = p2 + t[3];
            float ss = p3;
#pragma unroll
            for (int off = 1; off < 64; off <<= 1) {
                float tt = __shfl_up(ss, off);
                if (lane >= off) ss += tt;
            }
            float baseT = ss - p3;
            y[0] = fmaf((p0 + baseT) * fast_rcp(dAc[0] + 1e-12f), Cv[0][c], y[0]);
            y[1] = fmaf((p1 + baseT) * fast_rcp(dAc[1] + 1e-12f), Cv[1][c], y[1]);
            y[2] = fmaf((p2 + baseT) * fast_rcp(dAc[2] + 1e-12f), Cv[2][c], y[2]);
            y[3] = fmaf((p3 + baseT) * fast_rcp(dAc[3] + 1e-12f), Cv[3][c], y[3]);
        }
#pragma unroll
        for (int i = 0; i < 4; ++i) yred[w][l0 + i] = y[i];
        __syncthreads();

        int l = tid;
        float ysum = yred[0][l] + yred[1][l] + yred[2][l] + yred[3][l];
        float yv = fmaf(us[l], Dp[d], ysum);
        float res = xz[((size_t)(b * LL) + l) * 1024 + DI + d];
        ygT[(size_t)seq * LL + l] = yv * res * fast_sig(res);
    }
}

// ---------------- out-proj matvec (one column) into LDS ----------------
__device__ __forceinline__ void outproj_col(const float* __restrict__ ygT,
                                            const float* __restrict__ w1row,
                                            int b, int tid,
                                            float* ws, float* ms) {
    ws[tid] = w1row[tid];
    ws[tid + 256] = w1row[tid + 256];
    __syncthreads();
    const float* yb = ygT + (size_t)(b * 512) * 256 + tid;
    float a0 = 0.f, a1 = 0.f, a2 = 0.f, a3 = 0.f;
#pragma unroll 2
    for (int dd = 0; dd < 512; dd += 8) {
        float v0 = yb[(dd + 0) * 256], v1 = yb[(dd + 1) * 256];
        float v2 = yb[(dd + 2) * 256], v3 = yb[(dd + 3) * 256];
        float v4 = yb[(dd + 4) * 256], v5 = yb[(dd + 5) * 256];
        float v6 = yb[(dd + 6) * 256], v7 = yb[(dd + 7) * 256];
        a0 = fmaf(v0, ws[dd + 0], a0);
        a1 = fmaf(v1, ws[dd + 1], a1);
        a2 = fmaf(v2, ws[dd + 2], a2);
        a3 = fmaf(v3, ws[dd + 3], a3);
        a0 = fmaf(v4, ws[dd + 4], a0);
        a1 = fmaf(v5, ws[dd + 5], a1);
        a2 = fmaf(v6, ws[dd + 6], a2);
        a3 = fmaf(v7, ws[dd + 7], a3);
    }
    ms[tid] = (a0 + a1) + (a2 + a3);
    __syncthreads();
}

// ---------------- phase C fused with out-proj -> S0T coalesced ----------------
__global__ __launch_bounds__(256) void k_outproj_fuse_mean_h(const float* __restrict__ ygT,
                                                             const float* __restrict__ w1,
                                                             const float* __restrict__ x0,
                                                             float* __restrict__ S0T) {
    __shared__ float ws[512];
    __shared__ float ms[LL];
    int b, d; unswz(blockIdx.x, b, d);
    int bd = (b << 8) | d;
    int tid = threadIdx.x;
    outproj_col(ygT, w1 + (size_t)d * 512, b, tid, ws, ms);

    int w = tid;
    const float* xrow = x0 + (size_t)bd * 65536;
    float a0 = 0.0f, a1 = 0.0f, a2 = 0.0f, a3 = 0.0f;
    for (int h = 0; h < 256; h += 8) {
        float xv[8];
#pragma unroll
        for (int j = 0; j < 8; ++j) xv[j] = xrow[(size_t)(h + j) * 256 + w];
        a0 = fmaf(ms[h + 0], xv[0], a0);
        a1 = fmaf(ms[h + 1], xv[1], a1);
        a2 = fmaf(ms[h + 2], xv[2], a2);
        a3 = fmaf(ms[h + 3], xv[3], a3);
        a0 = fmaf(ms[h + 4], xv[4], a0);
        a1 = fmaf(ms[h + 5], xv[5], a1);
        a2 = fmaf(ms[h + 6], xv[6], a2);
        a3 = fmaf(ms[h + 7], xv[7], a3);
    }
    float acc = (a0 + a1) + (a2 + a3);
    S0T[(size_t)bd * 256 + w] = acc * (1.0f / 256.0f);   // coalesced row
}

// ---------------- phase E fused with out-proj ----------------
__global__ __launch_bounds__(256) void k_outproj_final(const float* __restrict__ ygT,
                                                       const float* __restrict__ w1,
                                                       const float* __restrict__ x0,
                                                       float* __restrict__ out) {
    __shared__ float ws[512];
    __shared__ float ms[LL];
    int b, d; unswz(blockIdx.x, b, d);
    int bd = (b << 8) | d;
    int tid = threadIdx.x;
    outproj_col(ygT, w1 + (size_t)d * 512, b, tid, ws, ms);

    int w4 = tid & 63;
    int hq = tid >> 6;
    float4 mv = *(const float4*)(ms + (w4 << 2));
    const float4* xin = (const float4*)(x0 + (size_t)bd * 65536);
    float4* oout = (float4*)(out + (size_t)bd * 65536);
#pragma unroll 4
    for (int hi = 0; hi < 64; ++hi) {
        int h = hi * 4 + hq;
        size_t idx = (size_t)h * 64 + w4;
        float4 xv = xin[idx];
        float4 o;
        o.x = mv.x * xv.x;
        o.y = mv.y * xv.y;
        o.z = mv.z * xv.z;
        o.w = mv.w * xv.w;
        oout[idx] = o;
    }
}

extern "C" void kernel_launch(void* const* d_in, const int* in_sizes, int n_in,
                              void* d_out, int out_size, void* d_ws, size_t ws_size,
                              hipStream_t stream) {
    const float* x0      = (const float*)d_in[0];
    const float* in_w    = (const float*)d_in[1];
    const float* conv_w  = (const float*)d_in[2];
    const float* conv_b  = (const float*)d_in[3];
    const float* xproj_w = (const float*)d_in[4];
    const float* dt_w    = (const float*)d_in[5];
    const float* dt_b    = (const float*)d_in[6];
    const float* A_log   = (const float*)d_in[7];
    const float* Dp      = (const float*)d_in[8];
    const float* out_w   = (const float*)d_in[9];
    float* out = (float*)d_out;

    float* S0T  = (float*)d_ws;        // 262144
    float* Wf   = S0T + 262144;        // 524288
    float* xz   = Wf + 524288;         // 1048576
    float* xdbl = xz + 1048576;        // 49152
    float* ygT  = xdbl + 49152;        // 524288

    const float* out_w1 = out_w + 131072;

    auto run_model_core = [&]() {
        k_gemm_tn_inproj<<<256, 256, 0, stream>>>(S0T, in_w, xz);
        k_mid<<<256, 256, 0, stream>>>(xz, conv_w, conv_b, xproj_w, xdbl);
        k_scan<<<512, 256, 0, stream>>>(xdbl, xz, conv_w, conv_b,
                                        A_log, Dp, dt_w, dt_b, ygT);
        k_gemm_tn64<<<256, 256, 0, stream>>>(ygT, Wf, xz);
        k_mid<<<256, 256, 0, stream>>>(xz, conv_w + 2048, conv_b + 512,
                                       xproj_w + 24576, xdbl);
        k_scan<<<512, 256, 0, stream>>>(xdbl, xz, conv_w + 2048, conv_b + 512,
                                        A_log + 8192, Dp + 512,
                                        dt_w + 8192, dt_b + 512, ygT);
    };

    k_meanw_prep<<<1536, 256, 0, stream>>>(x0, in_w + 262144, out_w, S0T, Wf);
    run_model_core();
    k_outproj_fuse_mean_h<<<NBL, 256, 0, stream>>>(ygT, out_w1, x0, S0T);
    run_model_core();
    k_outproj_final<<<NBL, 256, 0, stream>>>(ygT, out_w1, x0, out);
}

// Round 15
// 475.953 us; speedup vs baseline: 1.0106x; 1.0106x over previous
//
#include <hip/hip_runtime.h>
#include <math.h>

#define BSZ 4
#define DM 256
#define LL 256
#define DI 512
#define NBL (BSZ * LL)  // 1024

__device__ __forceinline__ float fast_rcp(float x) { return __builtin_amdgcn_rcpf(x); }
__device__ __forceinline__ float fast_sig(float x) { return fast_rcp(1.0f + __expf(-x)); }

// XCD batch-locality swizzle: launch index j -> (batch b, intra-batch i)
__device__ __forceinline__ void unswz(int j, int& b, int& i) {
    b = (j & 7) >> 1;
    i = ((j >> 3) << 1) | (j & 1);
}

// ---------------- dispatch 1: mean over W -> S0T[b][d][h] (blocks 0..1023) + Wf prep ----------------
__global__ __launch_bounds__(256) void k_meanw_prep(const float* __restrict__ x0,
                                                    const float* __restrict__ in_w1,
                                                    const float* __restrict__ out_w0,
                                                    float* __restrict__ S0T,
                                                    float* __restrict__ Wf) {
    __shared__ float smem[1664];
    int bl = blockIdx.x;
    int tid = threadIdx.x;
    if (bl < 1024) {
        int b, dch; unswz(bl, b, dch);
        int rowblk = (b << 8) | dch;
        int wv = tid >> 6, lane = tid & 63;
        const float4* x4 = (const float4*)x0;
        int rbase = rowblk * 256 + wv * 64;
        for (int i0 = 0; i0 < 64; i0 += 8) {
            float s[8];
#pragma unroll
            for (int j = 0; j < 8; ++j) {
                float4 v = x4[(size_t)(rbase + i0 + j) * 64 + lane];
                s[j] = (v.x + v.y) + (v.z + v.w);
            }
#pragma unroll
            for (int j = 0; j < 8; ++j) {
#pragma unroll
                for (int m = 32; m >= 1; m >>= 1) s[j] += __shfl_xor(s[j], m);
            }
            if (lane == 0) {
                float4 o1, o2;
                o1.x = s[0] * (1.0f / 256.0f); o1.y = s[1] * (1.0f / 256.0f);
                o1.z = s[2] * (1.0f / 256.0f); o1.w = s[3] * (1.0f / 256.0f);
                o2.x = s[4] * (1.0f / 256.0f); o2.y = s[5] * (1.0f / 256.0f);
                o2.z = s[6] * (1.0f / 256.0f); o2.w = s[7] * (1.0f / 256.0f);
                *(float4*)(S0T + (size_t)rbase + i0) = o1;
                *(float4*)(S0T + (size_t)rbase + i0 + 4) = o2;
            }
        }
    } else {
        float* As = smem;
        float* Bs = smem + 576;
        int t = bl - 1024;
        int e0 = (t >> 4) * 32, k0c = (t & 15) * 32;
        int tx = tid & 15, ty = tid >> 4;
        float acc00 = 0.f, acc01 = 0.f, acc10 = 0.f, acc11 = 0.f;
        for (int dm0 = 0; dm0 < 256; dm0 += 16) {
            float4 v;
            if (tid < 128) {
                int r = tid >> 2, q = tid & 3;
                v = *(const float4*)(in_w1 + (size_t)(e0 + r) * 256 + dm0 + 4 * q);
            } else {
                int idx = tid - 128;
                int r = idx >> 3, q = idx & 7;
                v = *(const float4*)(out_w0 + (size_t)(dm0 + r) * 512 + k0c + 4 * q);
            }
            __syncthreads();
            if (tid < 128) {
                int r = tid >> 2, q = tid & 3;
                As[(4 * q + 0) * 36 + r] = v.x;
                As[(4 * q + 1) * 36 + r] = v.y;
                As[(4 * q + 2) * 36 + r] = v.z;
                As[(4 * q + 3) * 36 + r] = v.w;
            } else {
                int idx = tid - 128;
                int r = idx >> 3, q = idx & 7;
                Bs[r * 36 + 4 * q + 0] = v.x;
                Bs[r * 36 + 4 * q + 1] = v.y;
                Bs[r * 36 + 4 * q + 2] = v.z;
                Bs[r * 36 + 4 * q + 3] = v.w;
            }
            __syncthreads();
#pragma unroll
            for (int kk = 0; kk < 16; ++kk) {
                float2 a = *(const float2*)(As + kk * 36 + 2 * ty);
                float2 b2 = *(const float2*)(Bs + kk * 36 + 2 * tx);
                acc00 = fmaf(a.x, b2.x, acc00);
                acc01 = fmaf(a.x, b2.y, acc01);
                acc10 = fmaf(a.y, b2.x, acc10);
                acc11 = fmaf(a.y, b2.y, acc11);
            }
        }
        float* c0 = Wf + (size_t)(e0 + 2 * ty) * 512 + k0c + 2 * tx;
        c0[0] = acc00; c0[1] = acc01;
        c0[512] = acc10; c0[513] = acc11;
    }
}

// ---------------- in-proj TN GEMM: xz[(b,l)][e] = sum_d S0T[b][d][l] * in_w[e][d], K=256 ----------------
__global__ __launch_bounds__(256) void k_gemm_tn_inproj(const float* __restrict__ S0T,
                                                        const float* __restrict__ Bw,
                                                        float* __restrict__ C) {
    __shared__ float As[16][68];
    __shared__ float Bs[16][68];
    int tid = threadIdx.x;
    int b, i; unswz(blockIdx.x, b, i);
    int l0 = (i >> 4) * 64;
    int n0 = (i & 15) * 64;
    int m0 = b * 256 + l0;
    int tx = tid & 15, ty = tid >> 4;
    int rkk = tid >> 4, mq = (tid & 15) * 4;
    int rn = tid >> 2, dq = (tid & 3) * 4;

    const float* pa = S0T + ((size_t)(b * 256) + rkk) * 256 + l0 + mq;
    const float* pb = Bw + (size_t)(n0 + rn) * 256 + dq;
    float4 ra = *(const float4*)pa;
    float4 rb = *(const float4*)pb;

    float acc[4][4];
#pragma unroll
    for (int ii = 0; ii < 4; ++ii)
#pragma unroll
        for (int jj = 0; jj < 4; ++jj) acc[ii][jj] = 0.0f;

    for (int d0 = 0; d0 < 256; d0 += 16) {
        __syncthreads();
        *(float4*)(&As[rkk][mq]) = ra;
        Bs[dq + 0][rn] = rb.x; Bs[dq + 1][rn] = rb.y; Bs[dq + 2][rn] = rb.z; Bs[dq + 3][rn] = rb.w;
        __syncthreads();
        if (d0 + 16 < 256) {
            ra = *(const float4*)(pa + (size_t)(d0 + 16) * 256);
            rb = *(const float4*)(pb + d0 + 16);
        }
#pragma unroll
        for (int kk = 0; kk < 16; ++kk) {
            float4 a4 = *(const float4*)(&As[kk][ty * 4]);
            float4 b4 = *(const float4*)(&Bs[kk][tx * 4]);
            float aa[4] = {a4.x, a4.y, a4.z, a4.w};
            float bb[4] = {b4.x, b4.y, b4.z, b4.w};
#pragma unroll
            for (int ii = 0; ii < 4; ++ii)
#pragma unroll
                for (int jj = 0; jj < 4; ++jj)
                    acc[ii][jj] = fmaf(aa[ii], bb[jj], acc[ii][jj]);
        }
    }
#pragma unroll
    for (int ii = 0; ii < 4; ++ii) {
        float4 o;
        o.x = acc[ii][0]; o.y = acc[ii][1]; o.z = acc[ii][2]; o.w = acc[ii][3];
        *(float4*)(C + (size_t)(m0 + ty * 4 + ii) * 1024 + n0 + tx * 4) = o;
    }
}

// ---------------- transition GEMM: 64x64 tile, K=512, grid 256 ----------------
__global__ __launch_bounds__(256) void k_gemm_tn64(const float* __restrict__ At,
                                                   const float* __restrict__ Bw,
                                                   float* __restrict__ C) {
    __shared__ float As[16][68];
    __shared__ float Bs[16][68];
    int tid = threadIdx.x;
    int b, i; unswz(blockIdx.x, b, i);
    int l0 = (i >> 4) * 64;
    int n0 = (i & 15) * 64;
    int m0 = b * 256 + l0;
    int tx = tid & 15, ty = tid >> 4;
    int rkk = tid >> 4, mq = (tid & 15) * 4;
    int rn = tid >> 2, dq = (tid & 3) * 4;

    const float* pa = At + ((size_t)(b * 512) + rkk) * 256 + l0 + mq;
    const float* pb = Bw + (size_t)(n0 + rn) * 512 + dq;
    float4 ra = *(const float4*)pa;
    float4 rb = *(const float4*)pb;

    float acc[4][4];
#pragma unroll
    for (int ii = 0; ii < 4; ++ii)
#pragma unroll
        for (int jj = 0; jj < 4; ++jj) acc[ii][jj] = 0.0f;

    for (int d0 = 0; d0 < 512; d0 += 16) {
        __syncthreads();
        *(float4*)(&As[rkk][mq]) = ra;
        Bs[dq + 0][rn] = rb.x; Bs[dq + 1][rn] = rb.y; Bs[dq + 2][rn] = rb.z; Bs[dq + 3][rn] = rb.w;
        __syncthreads();
        if (d0 + 16 < 512) {
            ra = *(const float4*)(pa + (size_t)(d0 + 16) * 256);
            rb = *(const float4*)(pb + d0 + 16);
        }
#pragma unroll
        for (int kk = 0; kk < 16; ++kk) {
            float4 a4 = *(const float4*)(&As[kk][ty * 4]);
            float4 b4 = *(const float4*)(&Bs[kk][tx * 4]);
            float aa[4] = {a4.x, a4.y, a4.z, a4.w};
            float bb[4] = {b4.x, b4.y, b4.z, b4.w};
#pragma unroll
            for (int ii = 0; ii < 4; ++ii)
#pragma unroll
                for (int jj = 0; jj < 4; ++jj)
                    acc[ii][jj] = fmaf(aa[ii], bb[jj], acc[ii][jj]);
        }
    }
#pragma unroll
    for (int ii = 0; ii < 4; ++ii) {
        float4 o;
        o.x = acc[ii][0]; o.y = acc[ii][1]; o.z = acc[ii][2]; o.w = acc[ii][3];
        *(float4*)(C + (size_t)(m0 + ty * 4 + ii) * 1024 + n0 + tx * 4) = o;
    }
}

// ---------------- mid: conv+silu+xproj -> xx + xdbl; 256 blocks x 4 (b,l) ----------------
__global__ __launch_bounds__(256) void k_mid(const float* __restrict__ xz,
                                             const float* __restrict__ cw,
                                             const float* __restrict__ cb,
                                             const float* __restrict__ xpw,
                                             float* __restrict__ xx,
                                             float* __restrict__ xdbl) {
    __shared__ float xs[DI];
    __shared__ float pr[256];
    int tid = threadIdx.x;
    int b = (blockIdx.x & 7) >> 1;
    int ib = ((blockIdx.x >> 3) << 1) | (blockIdx.x & 1);   // 0..63

    for (int k = 0; k < 4; ++k) {
        int l = ib + 64 * k;
        int bl = (b << 8) | l;
        __syncthreads();
#pragma unroll
        for (int c = 0; c < 2; ++c) {
            int d = tid + 256 * c;
            float4 w4 = *(const float4*)(cw + d * 4);
            float acc = cb[d];
#pragma unroll
            for (int kk = 0; kk < 4; ++kk) {
                int ls = l + kk - 3;
                float v = (ls >= 0) ? xz[((size_t)(b * LL + ls)) * 1024 + d] : 0.0f;
                acc = fmaf(((const float*)&w4)[kk], v, acc);
            }
            float v = acc * fast_sig(acc);
            xs[d] = v;
            xx[(size_t)bl * DI + d] = v;
        }
        __syncthreads();

        int e = tid >> 2, c2 = tid & 3;
        float a = 0.0f;
        if (e < 48) {
            const float4* xv4 = (const float4*)(xs + c2 * 128);
            const float4* wv4 = (const float4*)(xpw + (size_t)e * DI + c2 * 128);
#pragma unroll 8
            for (int q = 0; q < 32; ++q) {
                float4 x4 = xv4[q], p4 = wv4[q];
                a = fmaf(x4.x, p4.x, a);
                a = fmaf(x4.y, p4.y, a);
                a = fmaf(x4.z, p4.z, a);
                a = fmaf(x4.w, p4.w, a);
            }
        }
        pr[tid] = a;
        __syncthreads();
        if (tid < 48)
            xdbl[(size_t)bl * 48 + tid] = pr[4 * tid] + pr[4 * tid + 1] + pr[4 * tid + 2] + pr[4 * tid + 3];
    }
}

// ---------------- scan: 512 blocks x 4 sequences each (reads xx) ----------------
__global__ __launch_bounds__(256) void k_scan(const float* __restrict__ xx,
                                              const float* __restrict__ xdbl,
                                              const float* __restrict__ xz,
                                              const float* __restrict__ Alog,
                                              const float* __restrict__ Dp,
                                              const float* __restrict__ dtw,
                                              const float* __restrict__ dtb,
                                              float* __restrict__ ygT) {
    __shared__ float yred[4][LL];
    __shared__ float us[LL];
    int tid = threadIdx.x;
    int lane = tid & 63, w = tid >> 6;
    int b = (blockIdx.x & 7) >> 1;
    int ib = ((blockIdx.x >> 3) << 1) | (blockIdx.x & 1);   // 0..127
    int l0 = lane * 4;

    for (int kq = 0; kq < 4; ++kq) {
        int d = ib + 128 * kq;
        int seq = b * DI + d;
        __syncthreads();

        const float* xd0 = xdbl + ((size_t)(b * LL) + l0) * 48;
        const float* wr = dtw + d * 16;
        float4 w0 = *(const float4*)(wr + 0);
        float4 w1 = *(const float4*)(wr + 4);
        float4 w2 = *(const float4*)(wr + 8);
        float4 w3 = *(const float4*)(wr + 12);
        float bias = dtb[d];

        float dt[4], u[4], dtu[4], P[4];
#pragma unroll
        for (int i = 0; i < 4; ++i) {
            const float* xr = xd0 + i * 48;
            float4 a0 = *(const float4*)(xr + 0);
            float4 a1 = *(const float4*)(xr + 4);
            float4 a2 = *(const float4*)(xr + 8);
            float4 a3 = *(const float4*)(xr + 12);
            float acc = bias;
            acc = fmaf(a0.x, w0.x, acc); acc = fmaf(a0.y, w0.y, acc);
            acc = fmaf(a0.z, w0.z, acc); acc = fmaf(a0.w, w0.w, acc);
            acc = fmaf(a1.x, w1.x, acc); acc = fmaf(a1.y, w1.y, acc);
            acc = fmaf(a1.z, w1.z, acc); acc = fmaf(a1.w, w1.w, acc);
            acc = fmaf(a2.x, w2.x, acc); acc = fmaf(a2.y, w2.y, acc);
            acc = fmaf(a2.z, w2.z, acc); acc = fmaf(a2.w, w2.w, acc);
            acc = fmaf(a3.x, w3.x, acc); acc = fmaf(a3.y, w3.y, acc);
            acc = fmaf(a3.z, w3.z, acc); acc = fmaf(a3.w, w3.w, acc);
            dt[i] = (acc > 20.0f) ? acc : __logf(1.0f + __expf(acc));
            u[i] = xx[((size_t)(b * LL) + l0 + i) * DI + d];
            dtu[i] = dt[i] * u[i];
        }

        P[0] = dt[0]; P[1] = P[0] + dt[1]; P[2] = P[1] + dt[2]; P[3] = P[2] + dt[3];
        float s = P[3];
#pragma unroll
        for (int off = 1; off < 64; off <<= 1) {
            float t = __shfl_up(s, off);
            if (lane >= off) s += t;
        }
        float base = s - P[3];
        float dt_end = __shfl(s, 63);
        float Dtc[4];
#pragma unroll
        for (int i = 0; i < 4; ++i) Dtc[i] = P[i] + base;

        if (w == 0) {
#pragma unroll
            for (int i = 0; i < 4; ++i) us[l0 + i] = u[i];
        }

        float4 Al = *(const float4*)(Alog + d * 16 + 4 * w);
        float A[4] = {-__expf(Al.x), -__expf(Al.y), -__expf(Al.z), -__expf(Al.w)};
        float Bv[4][4], Cv[4][4];
#pragma unroll
        for (int i = 0; i < 4; ++i) {
            float4 bq = *(const float4*)(xd0 + i * 48 + 16 + 4 * w);
            float4 cq = *(const float4*)(xd0 + i * 48 + 32 + 4 * w);
            Bv[i][0] = bq.x; Bv[i][1] = bq.y; Bv[i][2] = bq.z; Bv[i][3] = bq.w;
            Cv[i][0] = cq.x; Cv[i][1] = cq.y; Cv[i][2] = cq.z; Cv[i][3] = cq.w;
        }

        float y[4] = {0.f, 0.f, 0.f, 0.f};
#pragma unroll
        for (int c = 0; c < 4; ++c) {
            float Ac = A[c];
            float dAc[4], t[4];
#pragma unroll
            for (int i = 0; i < 4; ++i) {
                dAc[i] = __expf(Ac * (dt_end - Dtc[i]));
                t[i] = dtu[i] * Bv[i][c] * dAc[i];
            }
            float p0 = t[0], p1 = p0 + t[1], p2 = p1 + t[2], p3 = p2 + t[3];
            float ss = p3;
#pragma unroll
            for (int off = 1; off < 64; off <<= 1) {
                float tt = __shfl_up(ss, off);
                if (lane >= off) ss += tt;
            }
            float baseT = ss - p3;
            y[0] = fmaf((p0 + baseT) * fast_rcp(dAc[0] + 1e-12f), Cv[0][c], y[0]);
            y[1] = fmaf((p1 + baseT) * fast_rcp(dAc[1] + 1e-12f), Cv[1][c], y[1]);
            y[2] = fmaf((p2 + baseT) * fast_rcp(dAc[2] + 1e-12f), Cv[2][c], y[2]);
            y[3] = fmaf((p3 + baseT) * fast_rcp(dAc[3] + 1e-12f), Cv[3][c], y[3]);
        }
#pragma unroll
        for (int i = 0; i < 4; ++i) yred[w][l0 + i] = y[i];
        __syncthreads();

        int l = tid;
        float ysum = yred[0][l] + yred[1][l] + yred[2][l] + yred[3][l];
        float yv = fmaf(us[l], Dp[d], ysum);
        float res = xz[((size_t)(b * LL) + l) * 1024 + DI + d];
        ygT[(size_t)seq * LL + l] = yv * res * fast_sig(res);
    }
}

// ---------------- out-proj matvec (one column) into LDS ----------------
__device__ __forceinline__ void outproj_col(const float* __restrict__ ygT,
                                            const float* __restrict__ w1row,
                                            int b, int tid,
                                            float* ws, float* ms) {
    ws[tid] = w1row[tid];
    ws[tid + 256] = w1row[tid + 256];
    __syncthreads();
    const float* yb = ygT + (size_t)(b * 512) * 256 + tid;
    float a0 = 0.f, a1 = 0.f, a2 = 0.f, a3 = 0.f;
#pragma unroll 2
    for (int dd = 0; dd < 512; dd += 8) {
        float v0 = yb[(dd + 0) * 256], v1 = yb[(dd + 1) * 256];
        float v2 = yb[(dd + 2) * 256], v3 = yb[(dd + 3) * 256];
        float v4 = yb[(dd + 4) * 256], v5 = yb[(dd + 5) * 256];
        float v6 = yb[(dd + 6) * 256], v7 = yb[(dd + 7) * 256];
        a0 = fmaf(v0, ws[dd + 0], a0);
        a1 = fmaf(v1, ws[dd + 1], a1);
        a2 = fmaf(v2, ws[dd + 2], a2);
        a3 = fmaf(v3, ws[dd + 3], a3);
        a0 = fmaf(v4, ws[dd + 4], a0);
        a1 = fmaf(v5, ws[dd + 5], a1);
        a2 = fmaf(v6, ws[dd + 6], a2);
        a3 = fmaf(v7, ws[dd + 7], a3);
    }
    ms[tid] = (a0 + a1) + (a2 + a3);
    __syncthreads();
}

// ---------------- phase C fused with out-proj -> S0T coalesced ----------------
__global__ __launch_bounds__(256) void k_outproj_fuse_mean_h(const float* __restrict__ ygT,
                                                             const float* __restrict__ w1,
                                                             const float* __restrict__ x0,
                                                             float* __restrict__ S0T) {
    __shared__ float ws[512];
    __shared__ float ms[LL];
    int b, d; unswz(blockIdx.x, b, d);
    int bd = (b << 8) | d;
    int tid = threadIdx.x;
    outproj_col(ygT, w1 + (size_t)d * 512, b, tid, ws, ms);

    int w = tid;
    const float* xrow = x0 + (size_t)bd * 65536;
    float a0 = 0.0f, a1 = 0.0f, a2 = 0.0f, a3 = 0.0f;
    for (int h = 0; h < 256; h += 8) {
        float xv[8];
#pragma unroll
        for (int j = 0; j < 8; ++j) xv[j] = xrow[(size_t)(h + j) * 256 + w];
        a0 = fmaf(ms[h + 0], xv[0], a0);
        a1 = fmaf(ms[h + 1], xv[1], a1);
        a2 = fmaf(ms[h + 2], xv[2], a2);
        a3 = fmaf(ms[h + 3], xv[3], a3);
        a0 = fmaf(ms[h + 4], xv[4], a0);
        a1 = fmaf(ms[h + 5], xv[5], a1);
        a2 = fmaf(ms[h + 6], xv[6], a2);
        a3 = fmaf(ms[h + 7], xv[7], a3);
    }
    float acc = (a0 + a1) + (a2 + a3);
    S0T[(size_t)bd * 256 + w] = acc * (1.0f / 256.0f);   // coalesced row
}

// ---------------- phase E fused with out-proj ----------------
__global__ __launch_bounds__(256) void k_outproj_final(const float* __restrict__ ygT,
                                                       const float* __restrict__ w1,
                                                       const float* __restrict__ x0,
                                                       float* __restrict__ out) {
    __shared__ float ws[512];
    __shared__ float ms[LL];
    int b, d; unswz(blockIdx.x, b, d);
    int bd = (b << 8) | d;
    int tid = threadIdx.x;
    outproj_col(ygT, w1 + (size_t)d * 512, b, tid, ws, ms);

    int w4 = tid & 63;
    int hq = tid >> 6;
    float4 mv = *(const float4*)(ms + (w4 << 2));
    const float4* xin = (const float4*)(x0 + (size_t)bd * 65536);
    float4* oout = (float4*)(out + (size_t)bd * 65536);
#pragma unroll 4
    for (int hi = 0; hi < 64; ++hi) {
        int h = hi * 4 + hq;
        size_t idx = (size_t)h * 64 + w4;
        float4 xv = xin[idx];
        float4 o;
        o.x = mv.x * xv.x;
        o.y = mv.y * xv.y;
        o.z = mv.z * xv.z;
        o.w = mv.w * xv.w;
        oout[idx] = o;
    }
}

extern "C" void kernel_launch(void* const* d_in, const int* in_sizes, int n_in,
                              void* d_out, int out_size, void* d_ws, size_t ws_size,
                              hipStream_t stream) {
    const float* x0      = (const float*)d_in[0];
    const float* in_w    = (const float*)d_in[1];
    const float* conv_w  = (const float*)d_in[2];
    const float* conv_b  = (const float*)d_in[3];
    const float* xproj_w = (const float*)d_in[4];
    const float* dt_w    = (const float*)d_in[5];
    const float* dt_b    = (const float*)d_in[6];
    const float* A_log   = (const float*)d_in[7];
    const float* Dp      = (const float*)d_in[8];
    const float* out_w   = (const float*)d_in[9];
    float* out = (float*)d_out;

    float* S0T  = (float*)d_ws;        // 262144
    float* Wf   = S0T + 262144;        // 524288
    float* xz   = Wf + 524288;         // 1048576
    float* xx   = xz + 1048576;        // 524288
    float* xdbl = xx + 524288;         // 49152
    float* ygT  = xdbl + 49152;        // 524288

    const float* out_w1 = out_w + 131072;

    auto run_model_core = [&]() {
        k_gemm_tn_inproj<<<256, 256, 0, stream>>>(S0T, in_w, xz);
        k_mid<<<256, 256, 0, stream>>>(xz, conv_w, conv_b, xproj_w, xx, xdbl);
        k_scan<<<512, 256, 0, stream>>>(xx, xdbl, xz, A_log, Dp, dt_w, dt_b, ygT);
        k_gemm_tn64<<<256, 256, 0, stream>>>(ygT, Wf, xz);
        k_mid<<<256, 256, 0, stream>>>(xz, conv_w + 2048, conv_b + 512,
                                       xproj_w + 24576, xx, xdbl);
        k_scan<<<512, 256, 0, stream>>>(xx, xdbl, xz, A_log + 8192, Dp + 512,
                                        dt_w + 8192, dt_b + 512, ygT);
    };

    k_meanw_prep<<<1536, 256, 0, stream>>>(x0, in_w + 262144, out_w, S0T, Wf);
    run_model_core();
    k_outproj_fuse_mean_h<<<NBL, 256, 0, stream>>>(ygT, out_w1, x0, S0T);
    run_model_core();
    k_outproj_final<<<NBL, 256, 0, stream>>>(ygT, out_w1, x0, out);
}